// Round 6
// baseline (416.668 us; speedup 1.0000x reference)
//
#include <hip/hip_runtime.h>
#include <stdint.h>

typedef unsigned short u16;
typedef unsigned int u32;
typedef __attribute__((ext_vector_type(8))) short bf16x8;
typedef __attribute__((ext_vector_type(4))) float f32x4;

__device__ __forceinline__ u16 f2bf(float f) {
  union { float f; u32 u; } x; x.f = f;
  return (u16)((x.u + 0x7FFFu + ((x.u >> 16) & 1u)) >> 16);
}

// Load 8 consecutive f32, round to bf16 (RTNE), return packed bf16x8.
__device__ __forceinline__ bf16x8 cvt8(const float* __restrict__ p) {
  const f32x4 v0 = *(const f32x4*)p;
  const f32x4 v1 = *(const f32x4*)(p + 4);
  bf16x8 o;
#pragma unroll
  for (int j = 0; j < 4; ++j) {
    o[j] = (short)f2bf(v0[j]);
    o[j + 4] = (short)f2bf(v1[j]);
  }
  return o;
}

// Stage a 128x128 f32 weight matrix (row-major W[n][k]) into LDS as bf16 with
// the G4 XOR swizzle: byte ^= (row&7)<<4.  256 threads * 8 chunks * 16B = 32KB.
__device__ __forceinline__ void stage_w(const float* __restrict__ Wg, u16* lds, int tid) {
#pragma unroll
  for (int i = 0; i < 8; ++i) {
    const int c = tid + i * 256;        // bf16 16B-chunk id, 0..2047
    const int n = c >> 4, k8 = c & 15;  // row, 8-elem group within row
    const bf16x8 w = cvt8(Wg + n * 128 + k8 * 8);
    const int b = (n * 256 + k8 * 16) ^ ((n & 7) << 4);
    *(bf16x8*)((char*)lds + b) = w;
  }
}

// One GEMM pass: acc[mt][nt] = A[mt] @ W^T (W staged swizzled in lds).
// A-frag: lane holds row lo (per mt sub-tile), k = kk*32 + hi*8 + j.
// Any HW K-slot permutation cancels: A and B use identical load mappings.
__device__ __forceinline__ void gemm_pass(const bf16x8 (&A)[2][4], const u16* Wl,
                                          int lo, int hi, int swb,
                                          f32x4 (&acc)[2][8]) {
  const f32x4 fzero = {0.f, 0.f, 0.f, 0.f};
#pragma unroll
  for (int mt = 0; mt < 2; ++mt)
#pragma unroll
    for (int nt = 0; nt < 8; ++nt) acc[mt][nt] = fzero;
#pragma unroll
  for (int kk = 0; kk < 4; ++kk)
#pragma unroll
    for (int nt = 0; nt < 8; ++nt) {
      const int n = nt * 16 + lo;
      const int b = n * 256 + ((kk * 64 + hi * 16) ^ swb);
      const bf16x8 w = *(const bf16x8*)((const char*)Wl + b);
      acc[0][nt] = __builtin_amdgcn_mfma_f32_16x16x32_bf16(A[0][kk], w, acc[0][nt], 0, 0, 0);
      acc[1][nt] = __builtin_amdgcn_mfma_f32_16x16x32_bf16(A[1][kk], w, acc[1][nt], 0, 0, 0);
    }
}

// v = ELU(h*z) computed in f32 C-layout regs, then bf16 -> swizzled
// wave-private 32x128 Z tile (intermediate layers only).
//   use1: value r of lane l is D[row=(l>>4)*4+r][col=l&15]
//  !use1: value r of lane l is D[row=l&15][col=(l>>4)*4+r]
__device__ __forceinline__ void combine_store(const f32x4 (&aH)[2][8], const f32x4 (&aZ)[2][8],
                                              u16* zw, int lo, int hi, bool use1) {
#pragma unroll
  for (int mt = 0; mt < 2; ++mt)
#pragma unroll
    for (int r = 0; r < 4; ++r)
#pragma unroll
      for (int nt = 0; nt < 8; ++nt) {
        const float v = aH[mt][nt][r] * aZ[mt][nt][r];
        const float e = __expf(v) - 1.0f;
        const u16 o = f2bf(v > 0.f ? v : e);
        const int m = mt * 16 + (use1 ? (hi * 4 + r) : lo);
        const int c = nt * 16 + (use1 ? lo : (hi * 4 + r));
        *(u16*)((char*)zw + ((m * 256) + ((c * 2) ^ ((m & 7) << 4)))) = o;
      }
}

// Read back A-layout frags from the wave-private Z tile.
__device__ __forceinline__ void zload(bf16x8 (&A)[2][4], const u16* zw,
                                      int lo, int hi, int swb) {
#pragma unroll
  for (int mt = 0; mt < 2; ++mt) {
    const int mb = (mt * 16 + lo) * 256;  // (m&7)==(lo&7) -> reuse swb
#pragma unroll
    for (int kk = 0; kk < 4; ++kk)
      A[mt][kk] = *(const bf16x8*)((const char*)zw + (mb + ((kk * 64 + hi * 16) ^ swb)));
  }
}

// Fully fused, no-workspace 3-layer edge pass. f32 inputs, **f32 output**
// (reference output dtype is float32 -> d_out is float*).
// grid = ceil(Ne/128), block = 256 (4 waves x 32 rows each).
__global__ __launch_bounds__(256, 2) void edge_fused_f32out_kernel(
    const float* __restrict__ E, const u32* __restrict__ SRC,
    const float* __restrict__ X,
    const float* __restrict__ Wn, const float* __restrict__ We,
    float* __restrict__ OUT, int Ne, int N) {
  __shared__ u16 Wl[128 * 128];   // 32 KiB staged weights (Wn then We per layer)
  __shared__ u16 Z[4][32 * 128];  // 32 KiB per-wave transpose staging

  const int tid = threadIdx.x;
  const int lane = tid & 63;
  const int wave = tid >> 6;
  const int lo = lane & 15, hi = lane >> 4;
  const int rowbase = blockIdx.x * 128 + wave * 32;
  const int swb = (lo & 7) << 4;
  const f32x4 fzero = {0.f, 0.f, 0.f, 0.f};

  // ---- C/D-mapping calibration probe (hardware-verified to select M1, kept
  // as ~free insurance): D = I(16x32-trunc) @ B, B[k][n]=2k+3n.
  bf16x8 pa, pb;
#pragma unroll
  for (int j = 0; j < 8; ++j) {
    const int k = hi * 8 + j;
    pa[j] = (short)f2bf(k == lo ? 1.0f : 0.0f);
    pb[j] = (short)f2bf(k < 16 ? (float)(2 * k + 3 * lo) : 0.0f);
  }
  const f32x4 pd = __builtin_amdgcn_mfma_f32_16x16x32_bf16(pa, pb, fzero, 0, 0, 0);
  bool am1 = true;
#pragma unroll
  for (int r = 0; r < 4; ++r)
    am1 = am1 && (pd[r] == (float)(2 * (hi * 4 + r) + 3 * lo));
  const bool use1 = (__all((int)am1) != 0);

  // ---- edge_sources dtype sniff: int64 iff first 16 odd u32 words all 0.
  bool is64 = true;
#pragma unroll
  for (int t = 1; t < 32; t += 2) is64 = is64 && (SRC[t] == 0u);

  int row[2];
  bf16x8 a[2][4];   // z A-frags
  bf16x8 xg[2][4];  // gathered X[src] A-frags (reused all 3 layers)
#pragma unroll
  for (int mt = 0; mt < 2; ++mt) {
    row[mt] = rowbase + mt * 16 + lo;
    const int rc = row[mt] < Ne ? row[mt] : 0;
    int s = (int)SRC[is64 ? (2 * rc) : rc];  // little-endian low word
    s = (s < 0 || s >= N) ? 0 : s;           // defensive clamp
    const float* __restrict__ p = E + (size_t)rc * 128;
    const float* __restrict__ px = X + (size_t)s * 128;
#pragma unroll
    for (int kk = 0; kk < 4; ++kk) {
      a[mt][kk] = cvt8(p + kk * 32 + hi * 8);
      xg[mt][kk] = cvt8(px + kk * 32 + hi * 8);
    }
  }

  u16* __restrict__ zw = &Z[wave][0];
  f32x4 accH[2][8], accZ[2][8];

  for (int layer = 0; layer < 3; ++layer) {
    // ---- h = Xg @ Wn[l]^T ----
    stage_w(Wn + layer * 16384, Wl, tid);
    __syncthreads();                       // Wn staged
    gemm_pass(xg, Wl, lo, hi, swb, accH);
    __syncthreads();                       // all Wn reads done before We staging

    // ---- zlin = z @ We[l]^T ----
    stage_w(We + layer * 16384, Wl, tid);
    __syncthreads();                       // We staged
    gemm_pass(a, Wl, lo, hi, swb, accZ);
    __syncthreads();                       // all We reads done before next stage

    if (layer < 2) {
      // ---- z = ELU(h*zlin) in f32, transpose back to A-frags via private Z.
      combine_store(accH, accZ, zw, lo, hi, use1);
      zload(a, zw, lo, hi, swb);           // wave-private: in-order DS, no barrier
    } else {
      // ---- final layer: ELU in f32 C-layout, store f32 directly ----
#pragma unroll
      for (int mt = 0; mt < 2; ++mt)
#pragma unroll
        for (int r = 0; r < 4; ++r) {
          const int m = mt * 16 + (use1 ? (hi * 4 + r) : lo);
          const int grow = rowbase + m;
          if (grow < Ne) {
            float* __restrict__ o = OUT + (size_t)grow * 128;
#pragma unroll
            for (int nt = 0; nt < 8; ++nt) {
              const float v = accH[mt][nt][r] * accZ[mt][nt][r];
              const float e = __expf(v) - 1.0f;
              const int c = nt * 16 + (use1 ? lo : (hi * 4 + r));
              o[c] = (v > 0.f ? v : e);
            }
          }
        }
    }
  }
}

extern "C" void kernel_launch(void* const* d_in, const int* in_sizes, int n_in,
                              void* d_out, int out_size, void* d_ws, size_t ws_size,
                              hipStream_t stream) {
  const float* X   = (const float*)d_in[0];  // input       [N][128] f32
  const u32*   SRC = (const u32*)d_in[1];    // edge_sources[Ne] int64 or int32
  const float* E   = (const float*)d_in[2];  // e           [Ne][128] f32
  const float* Wn  = (const float*)d_in[3];  // W_node      [3][128][128] f32
  const float* We  = (const float*)d_in[4];  // W_edge      [3][128][128] f32
  float* OUT = (float*)d_out;                // [Ne][128] f32

  const int N  = in_sizes[0] / 128;
  const int Ne = in_sizes[1];

  const int g = (Ne + 127) / 128;
  edge_fused_f32out_kernel<<<g, 256, 0, stream>>>(E, SRC, X, Wn, We, OUT, Ne, N);
}